// Round 8
// baseline (1787.059 us; speedup 1.0000x reference)
//
#include <hip/hip_runtime.h>

// Residual VQ: B=8,T=4096,D=128 -> N=32768 rows; 8 codebooks x 1024 codes.
// Outputs concat in d_out (float): codes [N*8], quantized [N*128], loss [1].
// R10: wave-wide codes + SGPR-resident A. 8 waves x 16 rows (MB=128, 256
// blocks = 1/CU), acc[16][4], PC=256/NPASS=4, K chunked 2x64.
// Per k4: ONE ds_read_b128 gather (lane l -> row l&15's quad) + 64 v_readlane
// -> A-scalars in SGPRs (lane-uniform rows), + 4 contiguous bv reads from
// [k4][code] float4 B tile staged via global_load_lds (zero staging VGPRs,
// linear dest -> conflict-free, mechanism proven in R8). LDS 5 reads/k4/wave
// (vs R2's 12); VALU-bound. Hot live ~100 VGPR (acc64+bv16+gather4).

#define N_ROWS 32768
#define DIM    128
#define KCB    1024
#define NCB    8
#define MB     128         // rows per block
#define PC     256         // codes per pass
#define NPASS  (KCB / PC)  // 4
#define KH     64          // k-chunk size (floats)
#define NCHUNK (DIM / KH)  // 2
#define LDA    132         // padded LDS row stride for A (floats): 528B, proven clean

typedef __attribute__((address_space(1))) const void GLOBv;
typedef __attribute__((address_space(3))) void LDSv;

__device__ __forceinline__ float rdlane(float v, int l) {
    return __builtin_bit_cast(float, __builtin_amdgcn_readlane(__builtin_bit_cast(int, v), l));
}

__global__ __launch_bounds__(256) void zero_ws_kernel(double* lws) {
    if (threadIdx.x < NCB) lws[threadIdx.x] = 0.0;
}

// c2[code] = numpy-pairwise sum over k of cb[code][k]^2 (n=128 pairwise, 8 accums)
__global__ __launch_bounds__(256) void c2_kernel(const float* __restrict__ cbw,
                                                 float* __restrict__ c2g) {
#pragma clang fp contract(off)
    int code = blockIdx.x * 256 + threadIdx.x;  // 0..8191
    const float* row = cbw + (size_t)code * DIM;
    float s[8];
    for (int j = 0; j < 8; ++j) { float x = row[j]; s[j] = x * x; }
    for (int m = 1; m < 16; ++m)
        for (int j = 0; j < 8; ++j) { float x = row[m * 8 + j]; float p = x * x; s[j] += p; }
    c2g[code] = ((s[0] + s[1]) + (s[2] + s[3])) + ((s[4] + s[5]) + (s[6] + s[7]));
}

__global__ __launch_bounds__(512, 2) void rvq_kernel(
    const float* __restrict__ emb, const float* __restrict__ cbw,
    const float* __restrict__ c2g, float* __restrict__ out,
    double* __restrict__ lws)
{
    __shared__ __align__(16) float a_lds[MB * LDA];   // residual [row][k] (67584 B)
    __shared__ float4 b_lds4[16 * PC];                // B chunk [k4][code] (65536 B)
    __shared__ float r2_lds[MB];
    __shared__ float c2_lds[PC];
    __shared__ float scr[4 * MB];                     // pairwise partials
    __shared__ float minv_lds[MB];                    // cross-pass argmin value
    __shared__ int   mini_lds[MB];                    // cross-pass argmin index
    __shared__ int   codes_lds[NCB * MB];

    const int tid  = threadIdx.x;
    const int tcol = tid & 63;   // 64 code-columns: codes tcol+64j, j<4
    const int trow = tid >> 6;   // 8 waves: wave w owns rows w*16 + i, i<16
    const size_t base = (size_t)blockIdx.x * MB;

    // ---- stage embeddings -> a_lds (residual): 4096 float4s, 8 per thread ----
#pragma unroll
    for (int s = 0; s < 8; ++s) {
        int f4 = s * 512 + tid;          // 0..4095
        int r = f4 >> 5, k4 = f4 & 31;
        float4 v = *(const float4*)(emb + (base + r) * DIM + (size_t)k4 * 4);
        *(float4*)(a_lds + r * LDA + k4 * 4) = v;
    }
    __syncthreads();

    // ---- initial r2: numpy pairwise (8 accums s_j; thread handles j in {2q,2q+1}) ----
    {
#pragma clang fp contract(off)
        int r = tid & 127, q = tid >> 7;   // q in 0..3
        float x0 = a_lds[r * LDA + 2 * q];     float s0 = x0 * x0;
        float x1 = a_lds[r * LDA + 2 * q + 1]; float s1 = x1 * x1;
        for (int m = 1; m < 16; ++m) {
            float y0 = a_lds[r * LDA + m * 8 + 2 * q];     float p0 = y0 * y0; s0 += p0;
            float y1 = a_lds[r * LDA + m * 8 + 2 * q + 1]; float p1 = y1 * y1; s1 += p1;
        }
        scr[q * MB + r] = s0 + s1;
    }
    __syncthreads();
    if (tid < MB) {
#pragma clang fp contract(off)
        float t0 = scr[tid], t1 = scr[MB + tid], t2 = scr[2 * MB + tid], t3 = scr[3 * MB + tid];
        r2_lds[tid] = (t0 + t1) + (t2 + t3);
    }
    // (pass-0 chunk-0 barrier below covers r2_lds/minv_lds visibility)

#pragma clang loop unroll(disable)
    for (int cb = 0; cb < NCB; ++cb) {
        const float* cbbase = cbw + (size_t)cb * KCB * DIM;
        if (tid < MB) minv_lds[tid] = 3.4e38f;

#pragma clang loop unroll(disable)
        for (int pass = 0; pass < NPASS; ++pass) {
            float acc[16][4];
#pragma unroll
            for (int i = 0; i < 16; ++i)
#pragma unroll
                for (int j = 0; j < 4; ++j) acc[i][j] = 0.f;

#pragma clang loop unroll(disable)
            for (int chunk = 0; chunk < NCHUNK; ++chunk) {
                __syncthreads();  // prior chunk's b_lds reads done; a_lds/r2/minv visible
                // stage B chunk [kk][code] via global_load_lds: combo = s*8+wave
                // -> (kk = combo>>2, code-group = combo&3); lane l fills code
                // cg*64+l at LDS slot kk*256+cg*64+l (linear dest, contiguous).
                {
                    const float* bsrc = cbbase + (size_t)pass * PC * DIM + chunk * KH;
#pragma unroll
                    for (int s = 0; s < 8; ++s) {
                        int combo = s * 8 + trow;         // 0..63, wave-uniform
                        int kk = combo >> 2, cg = combo & 3;
                        const float* g = bsrc + (size_t)(cg * 64 + tcol) * DIM + kk * 4;
                        float4* l = b_lds4 + kk * PC + cg * 64;   // wave-uniform base
                        __builtin_amdgcn_global_load_lds((GLOBv*)g, (LDSv*)l, 16, 0, 0);
                    }
                }
                if (chunk == 0 && tid < PC) c2_lds[tid] = c2g[cb * KCB + pass * PC + tid];
                __syncthreads();  // drains vmcnt(0): staged data visible

                // dots: 16 rows x 4 codes per thread, k ascending fp32 fma chains.
                // gather: lane l holds row (l&15)'s quad; v_readlane -> SGPR A.
                // bv: 64 contiguous float4s -> conflict-free.
                const float* agat = a_lds + (trow * 16 + (tid & 15)) * LDA + chunk * KH;
#pragma unroll
                for (int kk = 0; kk < 16; ++kk) {
                    float4 gq = *(const float4*)(agat + kk * 4);
                    float4 bv[4];
#pragma unroll
                    for (int j = 0; j < 4; ++j)
                        bv[j] = b_lds4[kk * PC + tcol + 64 * j];
#pragma unroll
                    for (int i = 0; i < 16; ++i) {
                        float a0 = rdlane(gq.x, i);
                        float a1 = rdlane(gq.y, i);
                        float a2 = rdlane(gq.z, i);
                        float a3 = rdlane(gq.w, i);
#pragma unroll
                        for (int j = 0; j < 4; ++j) {
                            acc[i][j] = fmaf(a0, bv[j].x, acc[i][j]);
                            acc[i][j] = fmaf(a1, bv[j].y, acc[i][j]);
                            acc[i][j] = fmaf(a2, bv[j].z, acc[i][j]);
                            acc[i][j] = fmaf(a3, bv[j].w, acc[i][j]);
                        }
                    }
                }
            }

            // per-pass epilogue: d2 = fl(fl(r2 - 2*dot) + c2); in-thread scan
            // (ascending cg, strict <) -> wave argmin -> lane0 merges into LDS.
            {
#pragma clang fp contract(off)
                float c2v[4];
#pragma unroll
                for (int j = 0; j < 4; ++j) c2v[j] = c2_lds[tcol + 64 * j];
#pragma unroll
                for (int i = 0; i < 16; ++i) {
                    int rr = trow * 16 + i;
                    float r2v = r2_lds[rr];
                    float v = 3.4e38f; int ix = 0;
#pragma unroll
                    for (int j = 0; j < 4; ++j) {
                        float t  = r2v - 2.0f * acc[i][j];
                        float d2 = t + c2v[j];
                        int   cg = pass * PC + tcol + 64 * j;
                        if (d2 < v) { v = d2; ix = cg; }
                    }
#pragma unroll
                    for (int m = 1; m <= 32; m <<= 1) {
                        float v2 = __shfl_xor(v, m, 64);
                        int  ix2 = __shfl_xor(ix, m, 64);
                        if (v2 < v || (v2 == v && ix2 < ix)) { v = v2; ix = ix2; }
                    }
                    if (tcol == 0) {
                        if (v < minv_lds[rr]) { minv_lds[rr] = v; mini_lds[rr] = ix; }
                    }
                }
            }
        }
        __syncthreads();  // mini_lds visible to all threads

        // residual update + loss + next-r2 pairwise partials (numpy order preserved)
        {
#pragma clang fp contract(off)
            int r = tid & 127, q = tid >> 7;
            int widx = mini_lds[r];
            if (q == 0) codes_lds[cb * MB + r] = widx;
            const float* ql = cbbase + (size_t)widx * DIM;
            float s0 = 0.f, s1 = 0.f;
            double lacc = 0.0;
            for (int m = 0; m < 16; ++m) {
                int k0 = m * 8 + 2 * q;
                float a0 = a_lds[r * LDA + k0];
                float q0 = ql[k0];
                float n0 = a0 - q0;           // new residual (exact ref op)
                a_lds[r * LDA + k0] = n0;
                float p0 = n0 * n0;           // loss element, fp32-rounded
                if (m == 0) s0 = p0; else s0 += p0;
                lacc += (double)p0;
                int k1 = k0 + 1;
                float a1 = a_lds[r * LDA + k1];
                float q1 = ql[k1];
                float n1 = a1 - q1;
                a_lds[r * LDA + k1] = n1;
                float p1 = n1 * n1;
                if (m == 0) s1 = p1; else s1 += p1;
                lacc += (double)p1;
            }
            scr[q * MB + r] = s0 + s1;
            for (int off = 32; off > 0; off >>= 1) lacc += __shfl_down(lacc, off, 64);
            if ((tid & 63) == 0) atomicAdd(&lws[cb], lacc);
        }
        __syncthreads();
        if (tid < MB) {
#pragma clang fp contract(off)
            float t0 = scr[tid], t1 = scr[MB + tid], t2 = scr[2 * MB + tid], t3 = scr[3 * MB + tid];
            r2_lds[tid] = (t0 + t1) + (t2 + t3);
        }
    }
    __syncthreads();

    // ---- write codes (as float) ----
    if (tid < MB) {
        int r = tid;
        float4 u, v;
        u.x = (float)codes_lds[0 * MB + r]; u.y = (float)codes_lds[1 * MB + r];
        u.z = (float)codes_lds[2 * MB + r]; u.w = (float)codes_lds[3 * MB + r];
        v.x = (float)codes_lds[4 * MB + r]; v.y = (float)codes_lds[5 * MB + r];
        v.z = (float)codes_lds[6 * MB + r]; v.w = (float)codes_lds[7 * MB + r];
        *(float4*)(out + (base + r) * NCB)     = u;
        *(float4*)(out + (base + r) * NCB + 4) = v;
    }

    // ---- quantized = emb + (quant - emb), quant = sequential fp32 sum of codewords ----
    {
#pragma clang fp contract(off)
        int r = tid >> 2, q4 = tid & 3;
        size_t rg = base + r;
        int cds[NCB];
#pragma unroll
        for (int cb = 0; cb < NCB; ++cb) cds[cb] = codes_lds[cb * MB + r];
        float* qout = out + (size_t)N_ROWS * NCB;
#pragma unroll
        for (int ii = 0; ii < 8; ++ii) {
            int k = q4 * 32 + ii * 4;
            float4 qv = make_float4(0.f, 0.f, 0.f, 0.f);
#pragma unroll
            for (int cb = 0; cb < NCB; ++cb) {
                float4 cv = *(const float4*)(cbw + ((size_t)cb * KCB + cds[cb]) * DIM + k);
                qv.x += cv.x; qv.y += cv.y; qv.z += cv.z; qv.w += cv.w;
            }
            float4 ev = *(const float4*)(emb + rg * DIM + k);
            float4 ov;
            ov.x = ev.x + (qv.x - ev.x);
            ov.y = ev.y + (qv.y - ev.y);
            ov.z = ev.z + (qv.z - ev.z);
            ov.w = ev.w + (qv.w - ev.w);
            *(float4*)(qout + rg * DIM + k) = ov;
        }
    }
}

__global__ __launch_bounds__(64) void finish_loss_kernel(const double* __restrict__ lws,
                                                         float* __restrict__ out_loss) {
    if (threadIdx.x == 0 && blockIdx.x == 0) {
        float l = 0.f;
        for (int cb = 0; cb < NCB; ++cb) {
            float m = (float)(lws[cb] / 4194304.0);  // mean over N*D
            l = l + m;                               // fp32 sequential adds (ref order)
        }
        out_loss[0] = l / 8.0f;
    }
}

extern "C" void kernel_launch(void* const* d_in, const int* in_sizes, int n_in,
                              void* d_out, int out_size, void* d_ws, size_t ws_size,
                              hipStream_t stream) {
    const float* emb = (const float*)d_in[0];   // [32768,128] fp32
    const float* cbw = (const float*)d_in[1];   // [8,1024,128] fp32
    float* out = (float*)d_out;
    double* lws = (double*)d_ws;                         // 8 doubles
    float* c2g = (float*)((char*)d_ws + 256);            // 8192 floats

    hipLaunchKernelGGL(zero_ws_kernel, dim3(1), dim3(64), 0, stream, lws);
    hipLaunchKernelGGL(c2_kernel, dim3(32), dim3(256), 0, stream, cbw, c2g);
    hipLaunchKernelGGL(rvq_kernel, dim3(256), dim3(512), 0, stream, emb, cbw, c2g, out, lws);
    hipLaunchKernelGGL(finish_loss_kernel, dim3(1), dim3(64), 0, stream, lws,
                       out + (size_t)N_ROWS * NCB + (size_t)N_ROWS * DIM);
}